// Round 13
// baseline (188.401 us; speedup 1.0000x reference)
//
#include <hip/hip_runtime.h>
#include <cstdint>
#include <cstddef>

#define BATCH 8
#define NODES 2048
#define IN_DIM 64
#define DTOT 128
#define NKEY 1024
#define QGROUPS 128    // 2048/16 row-groups per batch
#define KGROUPS 64     // 1024/16 u-groups per batch
#define SROW 1028      // score LDS row stride (f32): 2-way bank aliasing only (free)

typedef _Float16 half8v __attribute__((ext_vector_type(8)));
typedef float float4v __attribute__((ext_vector_type(4)));
typedef float float2v __attribute__((ext_vector_type(2)));

__device__ __forceinline__ unsigned long long make_key(float v, int idx) {
    unsigned u = __float_as_uint(v);
    u = (u & 0x80000000u) ? ~u : (u | 0x80000000u);
    return ((unsigned long long)u << 32) | (unsigned)(1023 - idx);
}

__device__ __forceinline__ float key_val(unsigned hi) {
    return __uint_as_float((hi & 0x80000000u) ? (hi & 0x7fffffffu) : ~hi);
}

// ---------------- Kernel 1: k-projection -> split-fp16 planes in MFMA-fragment layout ----------------
// Fragment layout: plane[b][g][h][l][e], flat = ((b*KGROUPS + g)*4 + h)*512 + l*8 + e
__global__ __launch_bounds__(256) void proj_k(
    const float* __restrict__ x, const float* __restrict__ Wk, const float* __restrict__ bk,
    _Float16* __restrict__ kfh, _Float16* __restrict__ kfl)
{
    __shared__ float xs[64 * 68];
    __shared__ float wsh[64 * 68];

    const int t = threadIdx.x;
    const int blk = blockIdx.x;
    const int b = blk >> 5;            // 32 blocks per batch
    const int idx = blk & 31;
    const int nbase = (idx >> 1) * 64;
    const int cbase = (idx & 1) * 64;
    const size_t gbase = (size_t)b * KGROUPS + (nbase >> 4);
    const int hbase = cbase >> 5;

    #pragma unroll
    for (int rep = 0; rep < 4; ++rep) {
        int f = rep * 256 + t;
        int r = f >> 4, d4 = f & 15;
        float4 xv = *(const float4*)(x + ((size_t)(b * NODES + nbase + r)) * IN_DIM + d4 * 4);
        *(float4*)(xs + r * 68 + d4 * 4) = xv;
        float4 wv = *(const float4*)(Wk + (size_t)(cbase + r) * IN_DIM + d4 * 4);
        *(float4*)(wsh + r * 68 + d4 * 4) = wv;
    }
    __syncthreads();

    const int w = t >> 6, l = t & 63;
    const int n_sel = w * 4 + (l >> 4);
    const int ul = l & 15;

    float acc[4][4];
    #pragma unroll
    for (int i = 0; i < 4; ++i)
        #pragma unroll
        for (int j = 0; j < 4; ++j) acc[i][j] = 0.f;

    #pragma unroll
    for (int d4 = 0; d4 < 16; ++d4) {
        float4 xv[4], wv[4];
        #pragma unroll
        for (int i = 0; i < 4; ++i)
            xv[i] = *(const float4*)(xs + (n_sel * 4 + i) * 68 + d4 * 4);
        #pragma unroll
        for (int j = 0; j < 4; ++j)
            wv[j] = *(const float4*)(wsh + (j * 16 + ul) * 68 + d4 * 4);
        #pragma unroll
        for (int i = 0; i < 4; ++i)
            #pragma unroll
            for (int j = 0; j < 4; ++j)
                acc[i][j] += xv[i].x * wv[j].x + xv[i].y * wv[j].y +
                             xv[i].z * wv[j].z + xv[i].w * wv[j].w;
    }
    __syncthreads();   // reuse xs as the 64x64 fp32 result tile

    #pragma unroll
    for (int j = 0; j < 4; ++j) {
        float bv = bk[cbase + j * 16 + ul];
        #pragma unroll
        for (int i = 0; i < 4; ++i)
            xs[(n_sel * 4 + i) * 68 + j * 16 + ul] = acc[i][j] + bv;
    }
    __syncthreads();

    #pragma unroll
    for (int rep = 0; rep < 2; ++rep) {
        int u = rep * 256 + t;
        int g = u >> 7, hh = (u >> 6) & 1, lf = u & 63;
        const float* src = xs + (g * 16 + (lf & 15)) * 68 + hh * 32 + (lf >> 4) * 8;
        float4 f0 = *(const float4*)src;
        float4 f1 = *(const float4*)(src + 4);
        float tmp[8] = {f0.x, f0.y, f0.z, f0.w, f1.x, f1.y, f1.z, f1.w};
        half8v hv, lv;
        #pragma unroll
        for (int e = 0; e < 8; ++e) {
            _Float16 hi = (_Float16)tmp[e];
            hv[e] = hi;
            lv[e] = (_Float16)(tmp[e] - (float)hi);
        }
        size_t dst = ((gbase + g) * 4 + hbase + hh) * (size_t)512 + lf * 8;
        *(half8v*)(kfh + dst) = hv;
        *(half8v*)(kfl + dst) = lv;
    }
}

// ---------------- Kernel 2: fused q-proj + MFMA scores + ballot top-32 + row write ----------------
// Block: 16 n-rows x 1024 u, 512 threads (8 waves). Prologue computes q for its 16 rows in-block
// (overlaid on sc LDS). Wave w: u-strip [w*128,+128) in the score phase (depth-1 B prefetch),
// rows {2w, 2w+1} in the select phase. b = blk&7 -> per-XCD batch affinity.
__global__ __launch_bounds__(512, 4) void scores_topk(
    const float* __restrict__ x, const float* __restrict__ Wq, const float* __restrict__ bq,
    const _Float16* __restrict__ kfh, const _Float16* __restrict__ kfl,
    const float* __restrict__ mlpw, const float* __restrict__ mlpb,
    float* __restrict__ adj)
{
    __shared__ float sc[16 * SROW];            // 64.25 KB scores
    __shared__ unsigned long long cand[8][64]; // 4 KB candidate buffers

    const int t = threadIdx.x;
    const int blk = blockIdx.x;
    const int b = blk & 7;                     // batch == XCD affinity (k stays L2-hot)
    const int gq = blk >> 3;                   // q row-group (16 rows)

    const int w = t >> 6, l = t & 63;
    const int quad = l >> 4, lane16 = l & 15;

    // ---- fused q projection for this block's 16 rows (LDS overlaid on sc) ----
    float* xq = sc;              // 16 x 68 fp32 (4.25 KB)
    float* qt = sc + 16 * 68;    // 16 x 132 fp32 (8.25 KB)

    if (t < 256) {               // load x tile: 16 rows x 64 f32 = 256 float4
        int r = t >> 4, d4 = t & 15;
        float4 v = *(const float4*)(x + ((size_t)(b * NODES + gq * 16 + r)) * IN_DIM + d4 * 4);
        *(float4*)(xq + r * 68 + d4 * 4) = v;
    }
    __syncthreads();

    {   // q GEMM: thread t -> col c = t&127, rows rg*4..rg*4+3 (rg = t>>7); q *= 1/sqrt(32)
        const int c = t & 127, rg = t >> 7;
        const float INVS = 0.17677669529663687f;
        float bv = bq[c];
        float acc[4] = {bv, bv, bv, bv};
        #pragma unroll
        for (int d4 = 0; d4 < 16; ++d4) {
            float4 w4 = *(const float4*)(Wq + (size_t)c * IN_DIM + d4 * 4);
            #pragma unroll
            for (int i = 0; i < 4; ++i) {
                float4 x4 = *(const float4*)(xq + (rg * 4 + i) * 68 + d4 * 4);
                acc[i] += w4.x * x4.x + w4.y * x4.y + w4.z * x4.z + w4.w * x4.w;
            }
        }
        __syncthreads();         // xq reads complete before qt writes (disjoint, but keep ordering w/ x loads)
        #pragma unroll
        for (int i = 0; i < 4; ++i)
            qt[(rg * 4 + i) * 132 + c] = acc[i] * INVS;
    }
    __syncthreads();

    // A fragments from qt: lane l -> row lane16, cols h*32 + quad*8 + e; split hi/lo fp16
    half8v Ah[4], Al[4];
    #pragma unroll
    for (int h = 0; h < 4; ++h) {
        const float* qp = qt + lane16 * 132 + h * 32 + quad * 8;
        float4 f0 = *(const float4*)qp;
        float4 f1 = *(const float4*)(qp + 4);
        float tmp[8] = {f0.x, f0.y, f0.z, f0.w, f1.x, f1.y, f1.z, f1.w};
        #pragma unroll
        for (int e = 0; e < 8; ++e) {
            _Float16 hi = (_Float16)tmp[e];
            Ah[h][e] = hi;
            Al[h][e] = (_Float16)(tmp[e] - (float)hi);
        }
    }
    __syncthreads();             // qt reads done before score phase overwrites sc

    float2v mw2[4][4], mb2[4];
    #pragma unroll
    for (int o = 0; o < 4; ++o) {
        float bvo = mlpb[o];
        mb2[o] = (float2v){bvo, bvo};
        #pragma unroll
        for (int h = 0; h < 4; ++h) {
            float mwo = mlpw[o * 4 + h];
            mw2[o][h] = (float2v){mwo, mwo};
        }
    }
    const float2v z2 = {0.f, 0.f};

    // ---- score phase with depth-1 software pipeline on B fragments ----
    half8v Bh[4], Bl[4];
    {
        size_t a0 = (((size_t)b * KGROUPS + w * 8) * 4) * (size_t)512 + l * 8;
        #pragma unroll
        for (int h = 0; h < 4; ++h) {
            Bh[h] = *(const half8v*)(kfh + a0 + h * 512);
            Bl[h] = *(const half8v*)(kfl + a0 + h * 512);
        }
    }

    #pragma unroll
    for (int i = 0; i < 8; ++i) {
        const int g = w * 8 + i;               // u-group
        half8v Bhn[4], Bln[4];
        if (i < 7) {                           // prefetch next u-group while MFMAs run
            size_t a1 = (((size_t)b * KGROUPS + g + 1) * 4) * (size_t)512 + l * 8;
            #pragma unroll
            for (int h = 0; h < 4; ++h) {
                Bhn[h] = *(const half8v*)(kfh + a1 + h * 512);
                Bln[h] = *(const half8v*)(kfl + a1 + h * 512);
            }
        }

        float4v C[4];
        #pragma unroll
        for (int h = 0; h < 4; ++h) {
            float4v c = {0.f, 0.f, 0.f, 0.f};
            c = __builtin_amdgcn_mfma_f32_16x16x32_f16(Ah[h], Bh[h], c, 0, 0, 0);
            c = __builtin_amdgcn_mfma_f32_16x16x32_f16(Ah[h], Bl[h], c, 0, 0, 0);
            c = __builtin_amdgcn_mfma_f32_16x16x32_f16(Al[h], Bh[h], c, 0, 0, 0);
            C[h] = c;
        }

        // packed epilogue: rows in pairs (v_pk_fma_f32 / v_pk_add_f32 / v_pk_max_f32)
        #pragma unroll
        for (int r2 = 0; r2 < 2; ++r2) {
            float2v a0 = {C[0][2 * r2], C[0][2 * r2 + 1]};
            float2v a1 = {C[1][2 * r2], C[1][2 * r2 + 1]};
            float2v a2 = {C[2][2 * r2], C[2][2 * r2 + 1]};
            float2v a3 = {C[3][2 * r2], C[3][2 * r2 + 1]};
            float2v ssum = ((a0 + a1) + a2) + a3;
            #pragma unroll
            for (int o = 0; o < 4; ++o) {
                float2v to = a0 * mw2[o][0] + a1 * mw2[o][1] +
                             a2 * mw2[o][2] + a3 * mw2[o][3] + mb2[o];
                ssum += __builtin_elementwise_max(to, z2);
            }
            const int col = g * 16 + lane16;
            sc[(quad * 4 + 2 * r2) * SROW + col] = ssum[0];
            sc[(quad * 4 + 2 * r2 + 1) * SROW + col] = ssum[1];
        }

        if (i < 7) {
            #pragma unroll
            for (int h = 0; h < 4; ++h) { Bh[h] = Bhn[h]; Bl[h] = Bln[h]; }
        }
    }
    __syncthreads();

    // ---- top-32 per row; wave w handles rows 2w, 2w+1; ranking via ballot (no DS traffic) ----
    for (int rr = 0; rr < 2; ++rr) {
        const int row = w * 2 + rr;
        float* R = sc + row * SROW;

        float4 vv[4];   // lane l holds u-indices jj*256 + l*4 + e
        #pragma unroll
        for (int jj = 0; jj < 4; ++jj) vv[jj] = *(const float4*)(R + jj * 256 + l * 4);

        float m = vv[0].x;
        #pragma unroll
        for (int jj = 0; jj < 4; ++jj) {
            m = fmaxf(m, vv[jj].x); m = fmaxf(m, vv[jj].y);
            m = fmaxf(m, vv[jj].z); m = fmaxf(m, vv[jj].w);
        }

        // T' = 32nd-largest lane-max truncated to 16 bits (T' <= exact T, still a valid bound)
        unsigned km;
        { unsigned s = __float_as_uint(m); km = (s & 0x80000000u) ? ~s : (s | 0x80000000u); }
        unsigned accT = 0u;
        #pragma unroll
        for (int bit = 31; bit >= 16; --bit) {
            unsigned trial = accT | (1u << bit);
            if (__popcll(__ballot(km >= trial)) >= 32) accT = trial;
        }
        const float T = key_val(accT);   // >= 32 row elements are >= T

        // ballot-compact candidates >= T into cand[w][]
        cand[w][l] = 0ull;
        __builtin_amdgcn_wave_barrier();
        int total = 0;
        #pragma unroll
        for (int jj = 0; jj < 4; ++jj) {
            #pragma unroll
            for (int e = 0; e < 4; ++e) {
                float v = (e == 0) ? vv[jj].x : (e == 1) ? vv[jj].y : (e == 2) ? vv[jj].z : vv[jj].w;
                bool p = (v >= T);
                unsigned long long msk = __ballot(p);
                if (p) {
                    int pos = total + __popcll(msk & ((1ull << l) - 1ull));
                    if (pos < 64) cand[w][pos] = make_key(v, jj * 256 + l * 4 + e);
                }
                total += (int)__popcll(msk);
            }
        }
        __builtin_amdgcn_wave_barrier();

        bool win = false; float wval = 0.f; int widx = 0;
        if (total <= 64) {
            unsigned long long key = cand[w][l];   // one key per lane (0 = empty, sorts last)
            unsigned hi = (unsigned)(key >> 32), lo = (unsigned)key;

            unsigned X = 0u;
            #pragma unroll
            for (int bit = 31; bit >= 0; --bit) {
                unsigned trial = X | (1u << bit);
                if (__popcll(__ballot(hi >= trial)) >= 32) X = trial;
            }
            int cgt = __popcll(__ballot(hi > X));
            int rem = 32 - cgt;
            unsigned Y = 0u;
            #pragma unroll
            for (int bit = 9; bit >= 0; --bit) {
                unsigned trial = Y | (1u << bit);
                if (__popcll(__ballot(hi == X && lo >= trial)) >= rem) Y = trial;
            }
            if (hi > X || (hi == X && lo >= Y)) {   // exactly 32 winners
                win = true;
                wval = key_val(hi);
                widx = 1023 - (int)lo;
            }
        } else {
            // rare fallback: exact 32-round butterfly extraction
            float vals[16];
            #pragma unroll
            for (int jj = 0; jj < 4; ++jj) {
                vals[jj * 4 + 0] = vv[jj].x; vals[jj * 4 + 1] = vv[jj].y;
                vals[jj * 4 + 2] = vv[jj].z; vals[jj * 4 + 3] = vv[jj].w;
            }
            float selv = 0.f; int seli = 0;
            #pragma unroll 1
            for (int it = 0; it < 32; ++it) {
                float bv = -3.4e38f; int bi = 0x7fffffff;
                #pragma unroll
                for (int s = 0; s < 16; ++s) {
                    int idx2 = (s >> 2) * 256 + l * 4 + (s & 3);
                    if (vals[s] > bv) { bv = vals[s]; bi = idx2; }
                }
                #pragma unroll
                for (int off = 1; off < 64; off <<= 1) {
                    float ov = __shfl_xor(bv, off, 64);
                    int oi = __shfl_xor(bi, off, 64);
                    if (ov > bv || (ov == bv && oi < bi)) { bv = ov; bi = oi; }
                }
                if (l == it) { selv = bv; seli = bi; }
                if (((bi >> 2) & 63) == l) {
                    int slot = ((bi >> 8) << 2) + (bi & 3);
                    #pragma unroll
                    for (int s = 0; s < 16; ++s) if (s == slot) vals[s] = -3.4e38f;
                }
            }
            if (l < 32) { win = true; wval = selv; widx = seli; }
        }

        // rebuild the row in place (DS pipe is in-order per wave): b128 zeros, scatter winner
        __builtin_amdgcn_wave_barrier();
        #pragma unroll
        for (int jj = 0; jj < 4; ++jj)
            *(float4*)(R + jj * 256 + l * 4) = make_float4(0.f, 0.f, 0.f, 0.f);
        __builtin_amdgcn_wave_barrier();
        if (win) R[widx] = wval;
        __builtin_amdgcn_wave_barrier();

        // final coalesced write of the 2048-wide row (upper half zeros)
        float* rowptr = adj + ((size_t)(b * NODES + gq * 16 + row)) * NODES;
        #pragma unroll
        for (int jj = 0; jj < 8; ++jj) {
            int c4 = jj * 64 + l;
            float4 val;
            if (c4 < 256) val = *(const float4*)(R + c4 * 4);
            else          val = make_float4(0.f, 0.f, 0.f, 0.f);
            *(float4*)(rowptr + c4 * 4) = val;
        }
    }
}

extern "C" void kernel_launch(void* const* d_in, const int* in_sizes, int n_in,
                              void* d_out, int out_size, void* d_ws, size_t ws_size,
                              hipStream_t stream) {
    const float* x    = (const float*)d_in[0];
    const float* Wq   = (const float*)d_in[1];
    const float* bq   = (const float*)d_in[2];
    const float* Wk   = (const float*)d_in[3];
    const float* bk   = (const float*)d_in[4];
    const float* mlpw = (const float*)d_in[5];
    const float* mlpb = (const float*)d_in[6];
    // ln_g, ln_b feed only the deleted adj_static -> unused.

    _Float16* kfh = (_Float16*)d_ws;                        // 2 MB
    _Float16* kfl = kfh + (size_t)BATCH * NKEY * DTOT;      // 2 MB (total 4 MB)
    float* adj = (float*)d_out;

    proj_k<<<dim3(BATCH * 32), dim3(256), 0, stream>>>(x, Wk, bk, kfh, kfl);
    scores_topk<<<dim3(BATCH * QGROUPS), dim3(512), 0, stream>>>(x, Wq, bq, kfh, kfl, mlpw, mlpb, adj);
}

// Round 14
// 183.121 us; speedup vs baseline: 1.0288x; 1.0288x over previous
//
#include <hip/hip_runtime.h>
#include <cstdint>
#include <cstddef>

#define BATCH 8
#define NODES 2048
#define IN_DIM 64
#define DTOT 128
#define NKEY 1024
#define QGROUPS 128    // 2048/16 row-groups per batch
#define KGROUPS 64     // 1024/16 u-groups per batch
#define SROW 1028      // score LDS row stride (f32): 2-way bank aliasing only (free)

typedef _Float16 half8v __attribute__((ext_vector_type(8)));
typedef float float4v __attribute__((ext_vector_type(4)));
typedef float float2v __attribute__((ext_vector_type(2)));

__device__ __forceinline__ unsigned long long make_key(float v, int idx) {
    unsigned u = __float_as_uint(v);
    u = (u & 0x80000000u) ? ~u : (u | 0x80000000u);
    return ((unsigned long long)u << 32) | (unsigned)(1023 - idx);
}

__device__ __forceinline__ float key_val(unsigned hi) {
    return __uint_as_float((hi & 0x80000000u) ? (hi & 0x7fffffffu) : ~hi);
}

// ---------------- Kernel 1: projection -> split-fp16 planes in MFMA-fragment layout ----------------
// Fragment layout: plane[b][g][h][l][e], flat = ((bG + g)*4 + h)*512 + l*8 + e
// q is pre-scaled by 1/sqrt(32) (k by 1.0 -> bit-exact) so the score epilogue drops 4 muls/elem.
__global__ __launch_bounds__(256) void proj_qk(
    const float* __restrict__ x, const float* __restrict__ Wq, const float* __restrict__ bq,
    const float* __restrict__ Wk, const float* __restrict__ bk,
    _Float16* __restrict__ qfh, _Float16* __restrict__ qfl,
    _Float16* __restrict__ kfh, _Float16* __restrict__ kfl)
{
    __shared__ float xs[64 * 68];
    __shared__ float wsh[64 * 68];

    const int t = threadIdx.x;
    const int blk = blockIdx.x;
    const int b = blk / 96;
    const int idx = blk - b * 96;

    const float* W; const float* bias;
    _Float16* oh; _Float16* ol;
    int nbase, cbase; size_t gbase;
    float scale;
    if (idx < 64) {
        int nt = idx >> 1, ct = idx & 1;
        nbase = nt * 64; cbase = ct * 64;
        W = Wq; bias = bq; oh = qfh; ol = qfl;
        gbase = (size_t)b * QGROUPS + (nbase >> 4);
        scale = 0.17677669529663687f;   // 1/sqrt(32)
    } else {
        int i2 = idx - 64;
        int nt = i2 >> 1, ct = i2 & 1;
        nbase = nt * 64; cbase = ct * 64;
        W = Wk; bias = bk; oh = kfh; ol = kfl;
        gbase = (size_t)b * KGROUPS + (nbase >> 4);
        scale = 1.0f;                   // exact no-op for k
    }
    const int hbase = cbase >> 5;

    #pragma unroll
    for (int rep = 0; rep < 4; ++rep) {
        int f = rep * 256 + t;
        int r = f >> 4, d4 = f & 15;
        float4 xv = *(const float4*)(x + ((size_t)(b * NODES + nbase + r)) * IN_DIM + d4 * 4);
        *(float4*)(xs + r * 68 + d4 * 4) = xv;
        float4 wv = *(const float4*)(W + (size_t)(cbase + r) * IN_DIM + d4 * 4);
        *(float4*)(wsh + r * 68 + d4 * 4) = wv;
    }
    __syncthreads();

    const int w = t >> 6, l = t & 63;
    const int n_sel = w * 4 + (l >> 4);
    const int ul = l & 15;

    float acc[4][4];
    #pragma unroll
    for (int i = 0; i < 4; ++i)
        #pragma unroll
        for (int j = 0; j < 4; ++j) acc[i][j] = 0.f;

    #pragma unroll
    for (int d4 = 0; d4 < 16; ++d4) {
        float4 xv[4], wv[4];
        #pragma unroll
        for (int i = 0; i < 4; ++i)
            xv[i] = *(const float4*)(xs + (n_sel * 4 + i) * 68 + d4 * 4);
        #pragma unroll
        for (int j = 0; j < 4; ++j)
            wv[j] = *(const float4*)(wsh + (j * 16 + ul) * 68 + d4 * 4);
        #pragma unroll
        for (int i = 0; i < 4; ++i)
            #pragma unroll
            for (int j = 0; j < 4; ++j)
                acc[i][j] += xv[i].x * wv[j].x + xv[i].y * wv[j].y +
                             xv[i].z * wv[j].z + xv[i].w * wv[j].w;
    }
    __syncthreads();   // reuse xs as the 64x64 fp32 result tile

    #pragma unroll
    for (int j = 0; j < 4; ++j) {
        float bv = bias[cbase + j * 16 + ul];
        #pragma unroll
        for (int i = 0; i < 4; ++i)
            xs[(n_sel * 4 + i) * 68 + j * 16 + ul] = (acc[i][j] + bv) * scale;
    }
    __syncthreads();

    #pragma unroll
    for (int rep = 0; rep < 2; ++rep) {
        int u = rep * 256 + t;
        int g = u >> 7, hh = (u >> 6) & 1, lf = u & 63;
        const float* src = xs + (g * 16 + (lf & 15)) * 68 + hh * 32 + (lf >> 4) * 8;
        float4 f0 = *(const float4*)src;
        float4 f1 = *(const float4*)(src + 4);
        float tmp[8] = {f0.x, f0.y, f0.z, f0.w, f1.x, f1.y, f1.z, f1.w};
        half8v hv, lv;
        #pragma unroll
        for (int e = 0; e < 8; ++e) {
            _Float16 hi = (_Float16)tmp[e];
            hv[e] = hi;
            lv[e] = (_Float16)(tmp[e] - (float)hi);
        }
        size_t dst = ((gbase + g) * 4 + hbase + hh) * (size_t)512 + lf * 8;
        *(half8v*)(oh + dst) = hv;
        *(half8v*)(ol + dst) = lv;
    }
}

// ---------------- Kernel 2: fused MFMA scores + ballot top-32 + final row write ----------------
// Block: 16 n-rows x 1024 u, 512 threads (8 waves). Wave w: u-strip [w*128, w*128+128) in the
// score phase (depth-1 B prefetch), rows {2w, 2w+1} in the select phase. b = blk&7 -> XCD affinity.
__global__ __launch_bounds__(512, 4) void scores_topk(
    const _Float16* __restrict__ qfh, const _Float16* __restrict__ qfl,
    const _Float16* __restrict__ kfh, const _Float16* __restrict__ kfl,
    const float* __restrict__ mlpw, const float* __restrict__ mlpb,
    float* __restrict__ adj)
{
    __shared__ float sc[16 * SROW];            // 64.25 KB scores
    __shared__ unsigned long long cand[8][64]; // 4 KB candidate buffers

    const int t = threadIdx.x;
    const int blk = blockIdx.x;
    const int b = blk & 7;                     // batch == XCD affinity (k stays L2-hot)
    const int gq = blk >> 3;                   // q row-group (16 rows)

    const int w = t >> 6, l = t & 63;
    const int quad = l >> 4, lane16 = l & 15;

    // A fragments: coalesced 16B loads from fragment-layout q
    half8v Ah[4], Al[4];
    #pragma unroll
    for (int h = 0; h < 4; ++h) {
        size_t a = (((size_t)b * QGROUPS + gq) * 4 + h) * 512 + l * 8;
        Ah[h] = *(const half8v*)(qfh + a);
        Al[h] = *(const half8v*)(qfl + a);
    }

    float2v mw2[4][4], mb2[4];
    #pragma unroll
    for (int o = 0; o < 4; ++o) {
        float bvo = mlpb[o];
        mb2[o] = (float2v){bvo, bvo};
        #pragma unroll
        for (int h = 0; h < 4; ++h) {
            float mwo = mlpw[o * 4 + h];
            mw2[o][h] = (float2v){mwo, mwo};
        }
    }
    const float2v z2 = {0.f, 0.f};

    // ---- score phase with depth-1 software pipeline on B fragments ----
    half8v Bh[4], Bl[4];
    {
        size_t a0 = (((size_t)b * KGROUPS + w * 8) * 4) * (size_t)512 + l * 8;
        #pragma unroll
        for (int h = 0; h < 4; ++h) {
            Bh[h] = *(const half8v*)(kfh + a0 + h * 512);
            Bl[h] = *(const half8v*)(kfl + a0 + h * 512);
        }
    }

    #pragma unroll
    for (int i = 0; i < 8; ++i) {
        const int g = w * 8 + i;               // u-group
        half8v Bhn[4], Bln[4];
        if (i < 7) {                           // prefetch next u-group while MFMAs run
            size_t a1 = (((size_t)b * KGROUPS + g + 1) * 4) * (size_t)512 + l * 8;
            #pragma unroll
            for (int h = 0; h < 4; ++h) {
                Bhn[h] = *(const half8v*)(kfh + a1 + h * 512);
                Bln[h] = *(const half8v*)(kfl + a1 + h * 512);
            }
        }

        float4v C[4];
        #pragma unroll
        for (int h = 0; h < 4; ++h) {
            float4v c = {0.f, 0.f, 0.f, 0.f};
            c = __builtin_amdgcn_mfma_f32_16x16x32_f16(Ah[h], Bh[h], c, 0, 0, 0);
            c = __builtin_amdgcn_mfma_f32_16x16x32_f16(Ah[h], Bl[h], c, 0, 0, 0);
            c = __builtin_amdgcn_mfma_f32_16x16x32_f16(Al[h], Bh[h], c, 0, 0, 0);
            C[h] = c;
        }

        // packed epilogue: rows in pairs (v_pk_fma_f32 / v_pk_add_f32 / v_pk_max_f32)
        #pragma unroll
        for (int r2 = 0; r2 < 2; ++r2) {
            float2v a0 = {C[0][2 * r2], C[0][2 * r2 + 1]};
            float2v a1 = {C[1][2 * r2], C[1][2 * r2 + 1]};
            float2v a2 = {C[2][2 * r2], C[2][2 * r2 + 1]};
            float2v a3 = {C[3][2 * r2], C[3][2 * r2 + 1]};
            float2v ssum = ((a0 + a1) + a2) + a3;
            #pragma unroll
            for (int o = 0; o < 4; ++o) {
                float2v to = a0 * mw2[o][0] + a1 * mw2[o][1] +
                             a2 * mw2[o][2] + a3 * mw2[o][3] + mb2[o];
                ssum += __builtin_elementwise_max(to, z2);
            }
            const int col = g * 16 + lane16;
            sc[(quad * 4 + 2 * r2) * SROW + col] = ssum[0];
            sc[(quad * 4 + 2 * r2 + 1) * SROW + col] = ssum[1];
        }

        if (i < 7) {
            #pragma unroll
            for (int h = 0; h < 4; ++h) { Bh[h] = Bhn[h]; Bl[h] = Bln[h]; }
        }
    }
    __syncthreads();

    // ---- top-32 per row; wave w handles rows 2w, 2w+1; ranking via ballot (no DS traffic) ----
    for (int rr = 0; rr < 2; ++rr) {
        const int row = w * 2 + rr;
        float* R = sc + row * SROW;

        float4 vv[4];   // lane l holds u-indices jj*256 + l*4 + e
        #pragma unroll
        for (int jj = 0; jj < 4; ++jj) vv[jj] = *(const float4*)(R + jj * 256 + l * 4);

        float m = vv[0].x;
        #pragma unroll
        for (int jj = 0; jj < 4; ++jj) {
            m = fmaxf(m, vv[jj].x); m = fmaxf(m, vv[jj].y);
            m = fmaxf(m, vv[jj].z); m = fmaxf(m, vv[jj].w);
        }

        // T = 32nd-largest lane-max, exact, via bitwise ballot search (order-preserving uint)
        unsigned km;
        { unsigned s = __float_as_uint(m); km = (s & 0x80000000u) ? ~s : (s | 0x80000000u); }
        unsigned accT = 0u;
        #pragma unroll
        for (int bit = 31; bit >= 0; --bit) {
            unsigned trial = accT | (1u << bit);
            if (__popcll(__ballot(km >= trial)) >= 32) accT = trial;
        }
        const float T = key_val(accT);   // >= 32 row elements are >= T, T <= true 32nd value

        // ballot-compact candidates >= T into cand[w][]
        cand[w][l] = 0ull;
        __builtin_amdgcn_wave_barrier();
        int total = 0;
        #pragma unroll
        for (int jj = 0; jj < 4; ++jj) {
            #pragma unroll
            for (int e = 0; e < 4; ++e) {
                float v = (e == 0) ? vv[jj].x : (e == 1) ? vv[jj].y : (e == 2) ? vv[jj].z : vv[jj].w;
                bool p = (v >= T);
                unsigned long long msk = __ballot(p);
                if (p) {
                    int pos = total + __popcll(msk & ((1ull << l) - 1ull));
                    if (pos < 64) cand[w][pos] = make_key(v, jj * 256 + l * 4 + e);
                }
                total += (int)__popcll(msk);
            }
        }
        __builtin_amdgcn_wave_barrier();

        bool win = false; float wval = 0.f; int widx = 0;
        if (total <= 64) {
            unsigned long long key = cand[w][l];   // one key per lane (0 = empty, sorts last)
            unsigned hi = (unsigned)(key >> 32), lo = (unsigned)key;

            unsigned X = 0u;
            #pragma unroll
            for (int bit = 31; bit >= 0; --bit) {
                unsigned trial = X | (1u << bit);
                if (__popcll(__ballot(hi >= trial)) >= 32) X = trial;
            }
            int cgt = __popcll(__ballot(hi > X));
            int rem = 32 - cgt;
            unsigned Y = 0u;
            #pragma unroll
            for (int bit = 9; bit >= 0; --bit) {
                unsigned trial = Y | (1u << bit);
                if (__popcll(__ballot(hi == X && lo >= trial)) >= rem) Y = trial;
            }
            if (hi > X || (hi == X && lo >= Y)) {   // exactly 32 winners
                win = true;
                wval = key_val(hi);
                widx = 1023 - (int)lo;
            }
        } else {
            // rare fallback: exact 32-round butterfly extraction
            float vals[16];
            #pragma unroll
            for (int jj = 0; jj < 4; ++jj) {
                vals[jj * 4 + 0] = vv[jj].x; vals[jj * 4 + 1] = vv[jj].y;
                vals[jj * 4 + 2] = vv[jj].z; vals[jj * 4 + 3] = vv[jj].w;
            }
            float selv = 0.f; int seli = 0;
            #pragma unroll 1
            for (int it = 0; it < 32; ++it) {
                float bv = -3.4e38f; int bi = 0x7fffffff;
                #pragma unroll
                for (int s = 0; s < 16; ++s) {
                    int idx2 = (s >> 2) * 256 + l * 4 + (s & 3);
                    if (vals[s] > bv) { bv = vals[s]; bi = idx2; }
                }
                #pragma unroll
                for (int off = 1; off < 64; off <<= 1) {
                    float ov = __shfl_xor(bv, off, 64);
                    int oi = __shfl_xor(bi, off, 64);
                    if (ov > bv || (ov == bv && oi < bi)) { bv = ov; bi = oi; }
                }
                if (l == it) { selv = bv; seli = bi; }
                if (((bi >> 2) & 63) == l) {
                    int slot = ((bi >> 8) << 2) + (bi & 3);
                    #pragma unroll
                    for (int s = 0; s < 16; ++s) if (s == slot) vals[s] = -3.4e38f;
                }
            }
            if (l < 32) { win = true; wval = selv; widx = seli; }
        }

        // rebuild the row in place (DS pipe is in-order per wave): b128 zeros, scatter winner
        __builtin_amdgcn_wave_barrier();
        #pragma unroll
        for (int jj = 0; jj < 4; ++jj)
            *(float4*)(R + jj * 256 + l * 4) = make_float4(0.f, 0.f, 0.f, 0.f);
        __builtin_amdgcn_wave_barrier();
        if (win) R[widx] = wval;
        __builtin_amdgcn_wave_barrier();

        // final coalesced write of the 2048-wide row (upper half zeros)
        float* rowptr = adj + ((size_t)(b * NODES + gq * 16 + row)) * NODES;
        #pragma unroll
        for (int jj = 0; jj < 8; ++jj) {
            int c4 = jj * 64 + l;
            float4 val;
            if (c4 < 256) val = *(const float4*)(R + c4 * 4);
            else          val = make_float4(0.f, 0.f, 0.f, 0.f);
            *(float4*)(rowptr + c4 * 4) = val;
        }
    }
}

extern "C" void kernel_launch(void* const* d_in, const int* in_sizes, int n_in,
                              void* d_out, int out_size, void* d_ws, size_t ws_size,
                              hipStream_t stream) {
    const float* x    = (const float*)d_in[0];
    const float* Wq   = (const float*)d_in[1];
    const float* bq   = (const float*)d_in[2];
    const float* Wk   = (const float*)d_in[3];
    const float* bk   = (const float*)d_in[4];
    const float* mlpw = (const float*)d_in[5];
    const float* mlpb = (const float*)d_in[6];
    // ln_g, ln_b feed only the deleted adj_static -> unused.

    _Float16* qfh = (_Float16*)d_ws;                        // 4 MB
    _Float16* qfl = qfh + (size_t)BATCH * NODES * DTOT;     // 4 MB
    _Float16* kfh = qfl + (size_t)BATCH * NODES * DTOT;     // 2 MB
    _Float16* kfl = kfh + (size_t)BATCH * NKEY * DTOT;      // 2 MB (total 12 MB)
    float* adj = (float*)d_out;

    proj_qk<<<dim3(BATCH * 96), dim3(256), 0, stream>>>(x, Wq, bq, Wk, bk, qfh, qfl, kfh, kfl);
    scores_topk<<<dim3(BATCH * QGROUPS), dim3(512), 0, stream>>>(qfh, qfl, kfh, kfl, mlpw, mlpb, adj);
}